// Round 3
// baseline (1318.036 us; speedup 1.0000x reference)
//
#include <hip/hip_runtime.h>
#include <math.h>

// ---------------------------------------------------------------------------
// GCN 165->32->16->2 + log_softmax, N=100k, E=3.2M.
//
// Round 3: kill the per-node CSR build (hist 3.2M global atomics + place
// 3.2M atomics with 15x write amplification = ~450us). Instead: coarse radix
// partition of edges into 782 buckets of 128 dst-nodes (LDS histograms, one
// global atomic per block*bucket, chunked writes of packed (local<<24)|src),
// then per-layer aggregation with one block per bucket: LDS f32 tile
// (stride padded to spread banks), LDS atomics, float4 line-gathers of
// hs[src], coalesced writeout. hs = dinv*(in@W); next-layer input
// relu(dinv*agg+b) stays fused into the next GEMM's read.
// ---------------------------------------------------------------------------

constexpr int NT = 256;
constexpr int NPB = 128;       // nodes per bucket
constexpr int LOG_NPB = 7;
constexpr int MAXBUK = 1024;
constexpr int EPB_A = 8192;    // edges per block, count pass
constexpr int EPB_B = 4096;    // edges per block, place pass

__global__ __launch_bounds__(NT) void count_kernel(const int* __restrict__ dst,
                                                   int* __restrict__ gcnt,
                                                   int E, int nbuk) {
    __shared__ int lh[MAXBUK];
    for (int i = threadIdx.x; i < nbuk; i += NT) lh[i] = 0;
    __syncthreads();
    int base = blockIdx.x * EPB_A;
#pragma unroll
    for (int i = 0; i < EPB_A / NT; i++) {
        int e = base + i * NT + threadIdx.x;
        if (e < E) atomicAdd(&lh[dst[e] >> LOG_NPB], 1);
    }
    __syncthreads();
    for (int i = threadIdx.x; i < nbuk; i += NT) {
        int v = lh[i];
        if (v) atomicAdd(&gcnt[i], v);
    }
}

__global__ __launch_bounds__(1024) void scan_kernel(const int* __restrict__ gcnt,
                                                    int* __restrict__ bptr,
                                                    int* __restrict__ cursor,
                                                    int nbuk, int E) {
    __shared__ int s[1024];
    int t = threadIdx.x;
    int v = (t < nbuk) ? gcnt[t] : 0;
    s[t] = v;
    __syncthreads();
    for (int off = 1; off < 1024; off <<= 1) {
        int a = (t >= off) ? s[t - off] : 0;
        __syncthreads();
        s[t] += a;
        __syncthreads();
    }
    if (t < nbuk) { int excl = s[t] - v; bptr[t] = excl; cursor[t] = excl; }
    if (t == 0) bptr[nbuk] = E;
}

__global__ __launch_bounds__(NT) void place_kernel(const int* __restrict__ src,
                                                   const int* __restrict__ dst,
                                                   int* __restrict__ cursor,
                                                   unsigned* __restrict__ ebuf,
                                                   int E, int nbuk) {
    __shared__ int lh[MAXBUK];
    __shared__ int lbase[MAXBUK];
    for (int i = threadIdx.x; i < nbuk; i += NT) lh[i] = 0;
    __syncthreads();
    constexpr int EPT = EPB_B / NT;  // 16
    unsigned pk[EPT];
    unsigned bl[EPT];
    int base = blockIdx.x * EPB_B;
#pragma unroll
    for (int i = 0; i < EPT; i++) {
        int e = base + i * NT + threadIdx.x;
        if (e < E) {
            int s = src[e], d = dst[e];
            int b = d >> LOG_NPB;
            int lp = atomicAdd(&lh[b], 1);
            pk[i] = ((unsigned)(d & (NPB - 1)) << 24) | (unsigned)s;
            bl[i] = ((unsigned)b << 16) | (unsigned)lp;
        } else {
            bl[i] = 0xFFFFFFFFu;
        }
    }
    __syncthreads();
    for (int i = threadIdx.x; i < nbuk; i += NT) {
        int v = lh[i];
        if (v) lbase[i] = atomicAdd(&cursor[i], v);
    }
    __syncthreads();
#pragma unroll
    for (int i = 0; i < EPT; i++) {
        if (bl[i] != 0xFFFFFFFFu) {
            int b = (int)(bl[i] >> 16);
            int lp = (int)(bl[i] & 0xFFFFu);
            ebuf[lbase[b] + lp] = pk[i];
        }
    }
}

// per-bucket degree count -> dinv
__global__ __launch_bounds__(NPB) void dinv_kernel(const unsigned* __restrict__ ebuf,
                                                   const int* __restrict__ bptr,
                                                   float* __restrict__ dinv, int N) {
    __shared__ int cnt[NPB];
    cnt[threadIdx.x] = 0;
    __syncthreads();
    int b = blockIdx.x;
    int s1 = bptr[b + 1];
    for (int i = bptr[b] + threadIdx.x; i < s1; i += NPB)
        atomicAdd(&cnt[ebuf[i] >> 24], 1);
    __syncthreads();
    int n = b * NPB + threadIdx.x;
    if (n < N) dinv[n] = rsqrtf((float)cnt[threadIdx.x] + 1.0f);
}

// FIRST=true: `in` is raw x[N,DIN]; else feature = relu(dinv[n]*in + bprev).
template <int DIN, int DOUT, bool FIRST>
__global__ __launch_bounds__(NT) void gemm_kernel(
    const float* __restrict__ in, const float* __restrict__ bprev,
    const float* __restrict__ W, const float* __restrict__ dinv,
    float* __restrict__ hs, int N) {
    __shared__ float Ws[DIN * DOUT];
    __shared__ float bs[FIRST ? 1 : DIN];
    int tid = threadIdx.x;
    for (int i = tid; i < DIN * DOUT; i += NT) Ws[i] = W[i];
    if (!FIRST) {
        for (int i = tid; i < DIN; i += NT) bs[i] = bprev[i];
    }
    __syncthreads();
    int n = blockIdx.x * NT + tid;
    if (n >= N) return;
    float dv = dinv[n];
    float acc[DOUT];
#pragma unroll
    for (int d = 0; d < DOUT; d++) acc[d] = 0.f;
    const float* row = in + (size_t)n * DIN;
    for (int k = 0; k < DIN; k++) {
        float xv;
        if (FIRST) {
            xv = row[k];
        } else {
            xv = fmaxf(fmaf(dv, row[k], bs[k]), 0.f);
        }
#pragma unroll
        for (int d = 0; d < DOUT; d++) acc[d] = fmaf(xv, Ws[k * DOUT + d], acc[d]);
    }
    float* hp = hs + (size_t)n * DOUT;
#pragma unroll
    for (int d = 0; d < DOUT; d++) hp[d] = dv * acc[d];
}

// One block per bucket. LDS tile with padded stride so LDS-atomic bank index
// depends on `local`, not just d (unpadded DOUT=32 => all 64 lanes same bank).
template <int DOUT, int STRIDE, bool FINAL>
__global__ __launch_bounds__(NT) void scatter_kernel(
    const float* __restrict__ hs, const unsigned* __restrict__ ebuf,
    const int* __restrict__ bptr, float* __restrict__ agg,
    const float* __restrict__ dinv, const float* __restrict__ bias,
    float* __restrict__ out, int N) {
    __shared__ float tile[NPB * STRIDE];
    int bkt = blockIdx.x;
    int nbase = bkt * NPB;
    int nn = min(NPB, N - nbase);
    // init with self message (coalesced scalar global reads)
    const float* hbase = hs + (size_t)nbase * DOUT;
    for (int idx = threadIdx.x; idx < nn * DOUT; idx += NT) {
        int local = idx / DOUT, d = idx % DOUT;
        tile[local * STRIDE + d] = hbase[idx];
    }
    __syncthreads();
    int s1 = bptr[bkt + 1];
    for (int i = bptr[bkt] + threadIdx.x; i < s1; i += NT) {
        unsigned p = ebuf[i];
        int local = (int)(p >> 24);
        int srcn = (int)(p & 0xFFFFFFu);
        float* tp = tile + local * STRIDE;
        if constexpr (DOUT == 2) {
            float2 v = *(const float2*)(hs + (size_t)srcn * 2);
            atomicAdd(&tp[0], v.x);
            atomicAdd(&tp[1], v.y);
        } else {
            const float4* hp4 = (const float4*)(hs + (size_t)srcn * DOUT);
#pragma unroll
            for (int q = 0; q < DOUT / 4; q++) {
                float4 v = hp4[q];
                atomicAdd(&tp[q * 4 + 0], v.x);
                atomicAdd(&tp[q * 4 + 1], v.y);
                atomicAdd(&tp[q * 4 + 2], v.z);
                atomicAdd(&tp[q * 4 + 3], v.w);
            }
        }
    }
    __syncthreads();
    if constexpr (!FINAL) {
        float* abase = agg + (size_t)nbase * DOUT;
        for (int idx = threadIdx.x; idx < nn * DOUT; idx += NT) {
            int local = idx / DOUT, d = idx % DOUT;
            abase[idx] = tile[local * STRIDE + d];
        }
    } else {
        if (threadIdx.x < nn) {
            int n = nbase + threadIdx.x;
            float dv = dinv[n];
            float z0 = fmaf(dv, tile[threadIdx.x * STRIDE + 0], bias[0]);
            float z1 = fmaf(dv, tile[threadIdx.x * STRIDE + 1], bias[1]);
            float m = fmaxf(z0, z1);
            float lse = m + logf(expf(z0 - m) + expf(z1 - m));
            out[(size_t)n * 2 + 0] = z0 - lse;
            out[(size_t)n * 2 + 1] = z1 - lse;
        }
    }
}

extern "C" void kernel_launch(void* const* d_in, const int* in_sizes, int n_in,
                              void* d_out, int out_size, void* d_ws, size_t ws_size,
                              hipStream_t stream) {
    const float* x  = (const float*)d_in[0];
    const int*   ei = (const int*)d_in[1];
    const float* W1 = (const float*)d_in[2];
    const float* b1 = (const float*)d_in[3];
    const float* W2 = (const float*)d_in[4];
    const float* b2 = (const float*)d_in[5];
    const float* W3 = (const float*)d_in[6];
    const float* b3 = (const float*)d_in[7];
    float* out = (float*)d_out;

    const int N = in_sizes[0] / 165;  // 100000
    const int E = in_sizes[1] / 2;    // 3200000
    const int* src = ei;
    const int* dst = ei + E;
    const int nbuk = (N + NPB - 1) >> LOG_NPB;  // 782
    const int NB = (N + NT - 1) / NT;           // 391

    char* p = (char*)d_ws;
    int* gcnt     = (int*)p;      p += (size_t)MAXBUK * 4;
    int* bptr     = (int*)p;      p += (size_t)(MAXBUK + 1) * 4;
    int* cursor   = (int*)p;      p += (size_t)MAXBUK * 4;
    unsigned* ebuf = (unsigned*)p; p += (size_t)E * 4;
    float* dinv   = (float*)p;    p += (size_t)N * 4;
    float* hs1    = (float*)p;    p += (size_t)N * 32 * 4;  // reused by hs2/agg2
    float* agg1   = (float*)p;    p += (size_t)N * 32 * 4;
    float* hs3    = (float*)p;    p += (size_t)N * 2 * 4;
    float* hs2    = hs1;                   // hs1 dead after scatter<32>
    float* agg2   = hs1 + (size_t)N * 16;

    hipMemsetAsync(gcnt, 0, (size_t)MAXBUK * sizeof(int), stream);
    count_kernel<<<(E + EPB_A - 1) / EPB_A, NT, 0, stream>>>(dst, gcnt, E, nbuk);
    scan_kernel<<<1, 1024, 0, stream>>>(gcnt, bptr, cursor, nbuk, E);
    place_kernel<<<(E + EPB_B - 1) / EPB_B, NT, 0, stream>>>(src, dst, cursor, ebuf, E, nbuk);
    dinv_kernel<<<nbuk, NPB, 0, stream>>>(ebuf, bptr, dinv, N);

    // Layer 1: 165 -> 32
    gemm_kernel<165, 32, true><<<NB, NT, 0, stream>>>(x, nullptr, W1, dinv, hs1, N);
    scatter_kernel<32, 33, false><<<nbuk, NT, 0, stream>>>(
        hs1, ebuf, bptr, agg1, nullptr, nullptr, nullptr, N);

    // Layer 2: 32 -> 16
    gemm_kernel<32, 16, false><<<NB, NT, 0, stream>>>(agg1, b1, W2, dinv, hs2, N);
    scatter_kernel<16, 17, false><<<nbuk, NT, 0, stream>>>(
        hs2, ebuf, bptr, agg2, nullptr, nullptr, nullptr, N);

    // Layer 3: 16 -> 2, scatter + bias + log_softmax fused
    gemm_kernel<16, 2, false><<<NB, NT, 0, stream>>>(agg2, b2, W3, dinv, hs3, N);
    scatter_kernel<2, 3, true><<<nbuk, NT, 0, stream>>>(
        hs3, ebuf, bptr, nullptr, dinv, b3, out, N);
}

// Round 4
// 447.552 us; speedup vs baseline: 2.9450x; 2.9450x over previous
//
#include <hip/hip_runtime.h>
#include <math.h>

// ---------------------------------------------------------------------------
// GCN 165->32->16->2 + log_softmax, N=100k, E=3.2M.
//
// Round 4: bucket partition (round 3, cheap: LDS histograms, one global
// atomic per block*bucket, chunked ebuf writes) + in-LDS per-bucket counting
// sort -> node-ordered esrc + rowptr + dinv (block-exclusive output range,
// no cross-XCD write amp) + round-2 register-accumulating gather (8 lanes
// per node, no atomics, 800k threads for latency hiding, unrolled x4).
// Round 3's LDS-atomic scatter (672us: 200k threads, serial dependent
// chains, occupancy 19.6%) is dead.
// hs = dinv*(in@W); agg[n] = hs[n] + sum_in hs[s];
// next-layer input relu(dinv*agg+b) fused into next GEMM's read.
// ---------------------------------------------------------------------------

constexpr int NT = 256;
constexpr int NPB = 128;       // nodes per bucket
constexpr int LOG_NPB = 7;
constexpr int MAXBUK = 1024;
constexpr int EPB_A = 8192;    // edges per block, count pass
constexpr int EPB_B = 4096;    // edges per block, place pass

__global__ __launch_bounds__(NT) void count_kernel(const int* __restrict__ dst,
                                                   int* __restrict__ gcnt,
                                                   int E, int nbuk) {
    __shared__ int lh[MAXBUK];
    for (int i = threadIdx.x; i < nbuk; i += NT) lh[i] = 0;
    __syncthreads();
    int base = blockIdx.x * EPB_A;
#pragma unroll
    for (int i = 0; i < EPB_A / NT; i++) {
        int e = base + i * NT + threadIdx.x;
        if (e < E) atomicAdd(&lh[dst[e] >> LOG_NPB], 1);
    }
    __syncthreads();
    for (int i = threadIdx.x; i < nbuk; i += NT) {
        int v = lh[i];
        if (v) atomicAdd(&gcnt[i], v);
    }
}

__global__ __launch_bounds__(1024) void scan_kernel(const int* __restrict__ gcnt,
                                                    int* __restrict__ bptr,
                                                    int* __restrict__ cursor,
                                                    int nbuk, int E) {
    __shared__ int s[1024];
    int t = threadIdx.x;
    int v = (t < nbuk) ? gcnt[t] : 0;
    s[t] = v;
    __syncthreads();
    for (int off = 1; off < 1024; off <<= 1) {
        int a = (t >= off) ? s[t - off] : 0;
        __syncthreads();
        s[t] += a;
        __syncthreads();
    }
    if (t < nbuk) { int excl = s[t] - v; bptr[t] = excl; cursor[t] = excl; }
    if (t == 0) bptr[nbuk] = E;
}

__global__ __launch_bounds__(NT) void place_kernel(const int* __restrict__ src,
                                                   const int* __restrict__ dst,
                                                   int* __restrict__ cursor,
                                                   unsigned* __restrict__ ebuf,
                                                   int E, int nbuk) {
    __shared__ int lh[MAXBUK];
    __shared__ int lbase[MAXBUK];
    for (int i = threadIdx.x; i < nbuk; i += NT) lh[i] = 0;
    __syncthreads();
    constexpr int EPT = EPB_B / NT;  // 16
    unsigned pk[EPT];
    unsigned bl[EPT];
    int base = blockIdx.x * EPB_B;
#pragma unroll
    for (int i = 0; i < EPT; i++) {
        int e = base + i * NT + threadIdx.x;
        if (e < E) {
            int s = src[e], d = dst[e];
            int b = d >> LOG_NPB;
            int lp = atomicAdd(&lh[b], 1);
            pk[i] = ((unsigned)(d & (NPB - 1)) << 24) | (unsigned)s;
            bl[i] = ((unsigned)b << 16) | (unsigned)lp;
        } else {
            bl[i] = 0xFFFFFFFFu;
        }
    }
    __syncthreads();
    for (int i = threadIdx.x; i < nbuk; i += NT) {
        int v = lh[i];
        if (v) lbase[i] = atomicAdd(&cursor[i], v);
    }
    __syncthreads();
#pragma unroll
    for (int i = 0; i < EPT; i++) {
        if (bl[i] != 0xFFFFFFFFu) {
            int b = (int)(bl[i] >> 16);
            int lp = (int)(bl[i] & 0xFFFFu);
            ebuf[lbase[b] + lp] = pk[i];
        }
    }
}

// One block per bucket: in-LDS counting sort of packed (local<<24)|src into
// node-ordered esrc; emits global rowptr and dinv. Output range is
// block-exclusive and contiguous -> no cross-XCD write amplification.
__global__ __launch_bounds__(NT) void sort_kernel(
    const unsigned* __restrict__ ebuf, const int* __restrict__ bptr,
    int* __restrict__ esrc, int* __restrict__ rowptr,
    float* __restrict__ dinv, int N, int E) {
    __shared__ int cnt[NPB];
    __shared__ int ofs[NPB];
    __shared__ int cur[NPB];
    int tid = threadIdx.x;
    int b = blockIdx.x;
    if (tid < NPB) cnt[tid] = 0;
    __syncthreads();
    int e0 = bptr[b], e1 = bptr[b + 1];
    for (int i = e0 + tid; i < e1; i += NT)
        atomicAdd(&cnt[ebuf[i] >> 24], 1);
    __syncthreads();
    if (tid < NPB) ofs[tid] = cnt[tid];
    __syncthreads();
    for (int off = 1; off < NPB; off <<= 1) {
        int a = (tid >= off && tid < NPB) ? ofs[tid - off] : 0;
        __syncthreads();
        if (tid < NPB) ofs[tid] += a;
        __syncthreads();
    }
    if (tid < NPB) {
        int excl = ofs[tid] - cnt[tid];
        cur[tid] = excl;
        int n = b * NPB + tid;
        if (n < N) {
            rowptr[n] = e0 + excl;
            dinv[n] = rsqrtf((float)cnt[tid] + 1.0f);
        }
    }
    if (b == 0 && tid == 0) rowptr[N] = E;
    __syncthreads();
    for (int i = e0 + tid; i < e1; i += NT) {
        unsigned p = ebuf[i];
        int l = (int)(p >> 24);
        int pos = atomicAdd(&cur[l], 1);
        esrc[e0 + pos] = (int)(p & 0xFFFFFFu);
    }
}

// FIRST=true: `in` is raw x[N,DIN]; else feature = relu(dinv[n]*in + bprev).
template <int DIN, int DOUT, bool FIRST>
__global__ __launch_bounds__(NT) void gemm_kernel(
    const float* __restrict__ in, const float* __restrict__ bprev,
    const float* __restrict__ W, const float* __restrict__ dinv,
    float* __restrict__ hs, int N) {
    __shared__ float Ws[DIN * DOUT];
    __shared__ float bs[FIRST ? 1 : DIN];
    int tid = threadIdx.x;
    for (int i = tid; i < DIN * DOUT; i += NT) Ws[i] = W[i];
    if (!FIRST) {
        for (int i = tid; i < DIN; i += NT) bs[i] = bprev[i];
    }
    __syncthreads();
    int n = blockIdx.x * NT + tid;
    if (n >= N) return;
    float dv = dinv[n];
    float acc[DOUT];
#pragma unroll
    for (int d = 0; d < DOUT; d++) acc[d] = 0.f;
    const float* row = in + (size_t)n * DIN;
    for (int k = 0; k < DIN; k++) {
        float xv;
        if (FIRST) {
            xv = row[k];
        } else {
            xv = fmaxf(fmaf(dv, row[k], bs[k]), 0.f);
        }
#pragma unroll
        for (int d = 0; d < DOUT; d++) acc[d] = fmaf(xv, Ws[k * DOUT + d], acc[d]);
    }
    float* hp = hs + (size_t)n * DOUT;
#pragma unroll
    for (int d = 0; d < DOUT; d++) hp[d] = dv * acc[d];
}

// DOUT/4 lanes per node, float4 chunks, register accumulation, no atomics.
// Unrolled x4 so each lane keeps 4 gathers in flight.
template <int DOUT>
__global__ __launch_bounds__(NT) void gather_kernel(
    const float* __restrict__ hs, const int* __restrict__ esrc,
    const int* __restrict__ rowptr, float* __restrict__ agg, int N) {
    constexpr int TPN = DOUT / 4;
    int gid = blockIdx.x * NT + threadIdx.x;
    int n = gid / TPN;
    int c = gid % TPN;
    if (n >= N) return;
    int j = rowptr[n];
    int end = rowptr[n + 1];
    const float4* base = (const float4*)hs;
    float4 acc = base[(size_t)n * TPN + c];  // self-loop message
    for (; j + 4 <= end; j += 4) {
        int s0 = esrc[j], s1 = esrc[j + 1], s2 = esrc[j + 2], s3 = esrc[j + 3];
        float4 v0 = base[(size_t)s0 * TPN + c];
        float4 v1 = base[(size_t)s1 * TPN + c];
        float4 v2 = base[(size_t)s2 * TPN + c];
        float4 v3 = base[(size_t)s3 * TPN + c];
        acc.x += v0.x + v1.x + v2.x + v3.x;
        acc.y += v0.y + v1.y + v2.y + v3.y;
        acc.z += v0.z + v1.z + v2.z + v3.z;
        acc.w += v0.w + v1.w + v2.w + v3.w;
    }
    for (; j < end; j++) {
        float4 v = base[(size_t)esrc[j] * TPN + c];
        acc.x += v.x; acc.y += v.y; acc.z += v.z; acc.w += v.w;
    }
    ((float4*)agg)[(size_t)n * TPN + c] = acc;
}

// Layer 3 gather (DOUT=2) fused with bias + log_softmax.
__global__ __launch_bounds__(NT) void final_kernel(
    const float* __restrict__ hs3, const int* __restrict__ esrc,
    const int* __restrict__ rowptr, const float* __restrict__ dinv,
    const float* __restrict__ b, float* __restrict__ out, int N) {
    int n = blockIdx.x * NT + threadIdx.x;
    if (n >= N) return;
    int j = rowptr[n];
    int end = rowptr[n + 1];
    const float2* h2 = (const float2*)hs3;
    float2 acc = h2[n];
    for (; j + 4 <= end; j += 4) {
        float2 v0 = h2[esrc[j]], v1 = h2[esrc[j + 1]];
        float2 v2 = h2[esrc[j + 2]], v3 = h2[esrc[j + 3]];
        acc.x += v0.x + v1.x + v2.x + v3.x;
        acc.y += v0.y + v1.y + v2.y + v3.y;
    }
    for (; j < end; j++) {
        float2 v = h2[esrc[j]];
        acc.x += v.x; acc.y += v.y;
    }
    float dv = dinv[n];
    float z0 = fmaf(dv, acc.x, b[0]);
    float z1 = fmaf(dv, acc.y, b[1]);
    float m = fmaxf(z0, z1);
    float lse = m + logf(expf(z0 - m) + expf(z1 - m));
    out[(size_t)n * 2 + 0] = z0 - lse;
    out[(size_t)n * 2 + 1] = z1 - lse;
}

extern "C" void kernel_launch(void* const* d_in, const int* in_sizes, int n_in,
                              void* d_out, int out_size, void* d_ws, size_t ws_size,
                              hipStream_t stream) {
    const float* x  = (const float*)d_in[0];
    const int*   ei = (const int*)d_in[1];
    const float* W1 = (const float*)d_in[2];
    const float* b1 = (const float*)d_in[3];
    const float* W2 = (const float*)d_in[4];
    const float* b2 = (const float*)d_in[5];
    const float* W3 = (const float*)d_in[6];
    const float* b3 = (const float*)d_in[7];
    float* out = (float*)d_out;

    const int N = in_sizes[0] / 165;  // 100000
    const int E = in_sizes[1] / 2;    // 3200000
    const int* src = ei;
    const int* dst = ei + E;
    const int nbuk = (N + NPB - 1) >> LOG_NPB;  // 782
    const int NB = (N + NT - 1) / NT;           // 391

    char* p = (char*)d_ws;
    int* gcnt      = (int*)p;      p += (size_t)MAXBUK * 4;
    int* bptr      = (int*)p;      p += (size_t)(MAXBUK + 1) * 4;
    int* cursor    = (int*)p;      p += (size_t)MAXBUK * 4;
    unsigned* ebuf = (unsigned*)p; p += (size_t)E * 4;
    int* esrc      = (int*)p;      p += (size_t)E * 4;
    int* rowptr    = (int*)p;      p += (size_t)(N + 1) * 4;
    float* dinv    = (float*)p;    p += (size_t)N * 4;
    float* hs1     = (float*)p;    p += (size_t)N * 32 * 4;  // reused by hs2/agg2
    float* agg1    = (float*)p;    p += (size_t)N * 32 * 4;
    float* hs3     = (float*)p;    p += (size_t)N * 2 * 4;
    float* hs2     = hs1;                   // hs1 dead after gather<32>
    float* agg2    = hs1 + (size_t)N * 16;

    hipMemsetAsync(gcnt, 0, (size_t)MAXBUK * sizeof(int), stream);
    count_kernel<<<(E + EPB_A - 1) / EPB_A, NT, 0, stream>>>(dst, gcnt, E, nbuk);
    scan_kernel<<<1, 1024, 0, stream>>>(gcnt, bptr, cursor, nbuk, E);
    place_kernel<<<(E + EPB_B - 1) / EPB_B, NT, 0, stream>>>(src, dst, cursor, ebuf, E, nbuk);
    sort_kernel<<<nbuk, NT, 0, stream>>>(ebuf, bptr, esrc, rowptr, dinv, N, E);

    // Layer 1: 165 -> 32
    gemm_kernel<165, 32, true><<<NB, NT, 0, stream>>>(x, nullptr, W1, dinv, hs1, N);
    gather_kernel<32><<<((size_t)N * 8 + NT - 1) / NT, NT, 0, stream>>>(
        hs1, esrc, rowptr, agg1, N);

    // Layer 2: 32 -> 16
    gemm_kernel<32, 16, false><<<NB, NT, 0, stream>>>(agg1, b1, W2, dinv, hs2, N);
    gather_kernel<16><<<((size_t)N * 4 + NT - 1) / NT, NT, 0, stream>>>(
        hs2, esrc, rowptr, agg2, N);

    // Layer 3: 16 -> 2, gather + bias + log_softmax fused
    gemm_kernel<16, 2, false><<<NB, NT, 0, stream>>>(agg2, b2, W3, dinv, hs3, N);
    final_kernel<<<NB, NT, 0, stream>>>(hs3, esrc, rowptr, dinv, b3, out, N);
}